// Round 5
// baseline (522.359 us; speedup 1.0000x reference)
//
#include <hip/hip_runtime.h>

typedef __attribute__((ext_vector_type(4))) float fv4;
typedef __attribute__((ext_vector_type(8))) _Float16 hv8;
typedef __attribute__((ext_vector_type(4))) _Float16 hv4;
typedef __attribute__((ext_vector_type(2))) _Float16 hv2;

// ---------------------------------------------------------------------------
// async global->LDS 16B copy (wave-uniform LDS base + lane*16 semantics)
// ---------------------------------------------------------------------------
__device__ __forceinline__ void gload16(const void* g, void* l) {
  __builtin_amdgcn_global_load_lds(
      (const __attribute__((address_space(1))) unsigned int*)g,
      (__attribute__((address_space(3))) unsigned int*)l, 16, 0, 0);
}

// ---------------------------------------------------------------------------
// 256x128 tile GEMM core, 4 waves (2M x 2N), per-wave 128x64 output.
// LDS: 3-slot ring of 24 KiB (A 256x32 + B 128x32) = 72 KiB -> TWO blocks
// co-resident per CU. The 2 waves on each SIMD then belong to DIFFERENT
// blocks with independent barrier domains: one block's LDS-read burst and
// barrier stall overlaps the other block's MFMA cluster (m114 overlap).
// This attacks the ~900 cyc/K-step convergence stall that R1-R4's ILP
// variants (phase split, single barrier, reg prefetch) could not remove at
// 1-block lockstep.
// K-step (1 barrier): vmcnt(6) [slot s mine landed; only slot s+1's 6 may
// remain in flight] -> s_barrier [collective: slot s landed, reads of s-1
// done] -> 12 ds_read_b128 (slot s) -> stage slot s+2 (safe: overwrites
// (s-1)%3 whose reads the barrier certified) -> setprio(1) 32 MFMA.
// vmcnt never drains to 0 in the main loop (tail 6 -> 0).
// Swizzle (measured 0 conflicts): LDS(row,oct) holds global col-octet
// oct ^ ((row>>1)&3); staged via cg=(lane&3)^((lane>>3)&3) pre-swizzled
// global source (row = .. + (lane>>2) => (row>>1)&3 == (lane>>3)&3);
// fragment read at oct = quad ^ ((r>>1)&3) retrieves octet 'quad'.
// ---------------------------------------------------------------------------
struct GemmCore128 {
  const _Float16 *ap, *bp;   // per-thread pre-swizzled global sources
  size_t rstep;              // +64 rows in elements
  _Float16* ls;
  const _Float16 *fa, *fb;   // fragment read bases (ring slot 0)
  int wv;

  __device__ __forceinline__ void init(const _Float16* A, const _Float16* Bt,
                                       _Float16* lds, int m0, int n0, int K,
                                       int tid) {
    ls = lds;
    wv = tid >> 6;
    const int lane = tid & 63;
    const int wm = wv >> 1, wn = wv & 1;
    const int quad = lane >> 4, r = lane & 15;
    const int cg = (lane & 3) ^ ((lane >> 3) & 3);   // staged-side XOR swizzle
    const int rb = wv * 16 + (lane >> 2);            // staging row base
    ap = A  + (size_t)(m0 + rb) * K + cg * 8;
    bp = Bt + (size_t)(n0 + rb) * K + cg * 8;
    rstep = (size_t)64 * K;
    const int sq = quad ^ ((r >> 1) & 3);            // fragment-side swizzle
    fa = ls + (wm * 128 + r) * 32 + sq * 8;
    fb = ls + 8192 + (wn * 64 + r) * 32 + sq * 8;
  }

  // stage K-step s into ring slot s%3: 6 x 16B per thread (4 A rows, 2 B)
  __device__ __forceinline__ void stage(int s) {
    _Float16* d = ls + (s % 3) * 12288 + wv * 512;
    const _Float16* a = ap + (size_t)s * 32;
    const _Float16* b = bp + (size_t)s * 32;
    gload16(a,             d);
    gload16(a + rstep,     d + 2048);
    gload16(a + 2 * rstep, d + 4096);
    gload16(a + 3 * rstep, d + 6144);
    gload16(b,             d + 8192);
    gload16(b + rstep,     d + 10240);
  }

  // one K-step: vmcnt(VM) -> barrier -> 12 reads -> stage(s+2) -> 32 MFMA
  template <int VM, bool STAGE>
  __device__ __forceinline__ void body(fv4 acc[8][4], int s) {
    asm volatile("s_waitcnt vmcnt(%0)" :: "n"(VM) : "memory");
    __builtin_amdgcn_s_barrier();
    asm volatile("" ::: "memory");   // pin LDS reads/stage below the barrier
    const int sl = s % 3;
    const _Float16* fA = fa + sl * 12288;
    const _Float16* fB = fb + sl * 12288;
    hv8 a0[8], b0[4];
#pragma unroll
    for (int t = 0; t < 4; ++t) a0[t] = *(const hv8*)(fA + t * 512);
#pragma unroll
    for (int t = 0; t < 4; ++t) b0[t] = *(const hv8*)(fB + t * 512);
#pragma unroll
    for (int t = 0; t < 4; ++t) a0[t + 4] = *(const hv8*)(fA + (t + 4) * 512);
    if (STAGE) stage(s + 2);         // overwrites slot (s-1)%3: reads certified
    __builtin_amdgcn_s_setprio(1);
#pragma unroll
    for (int tm = 0; tm < 4; ++tm)
#pragma unroll
      for (int tn = 0; tn < 4; ++tn)
        acc[tm][tn] = __builtin_amdgcn_mfma_f32_16x16x32_f16(a0[tm], b0[tn],
                                                             acc[tm][tn], 0, 0, 0);
#pragma unroll
    for (int tm = 0; tm < 4; ++tm)
#pragma unroll
      for (int tn = 0; tn < 4; ++tn)
        acc[tm + 4][tn] = __builtin_amdgcn_mfma_f32_16x16x32_f16(a0[tm + 4], b0[tn],
                                                                 acc[tm + 4][tn], 0, 0, 0);
    __builtin_amdgcn_s_setprio(0);
  }

  __device__ __forceinline__ void run(fv4 acc[8][4], int K) {
    const int ns = K >> 5;               // BK=32 steps (K = 512 or 1024)
    stage(0); stage(1);                  // prime ring 2 deep (12 outstanding)
    int s = 0;
    for (; s <= ns - 3; ++s) body<6, true>(acc, s);   // stages s+2
    body<6, false>(acc, s); ++s;         // tail guards: 6 -> 0
    body<0, false>(acc, s);
  }
};

// XCD-colocation block swizzle (tile 256M x 128N): blocks sharing one A-strip
// get linear ids congruent mod 8 -> same XCD -> A-strip hits in its L2.
__device__ __forceinline__ void xcd_map(int bid, int ntl2, int mt_per_x,
                                        int& m0, int& n0) {
  const int xcd = bid & 7;
  const int k2  = bid >> 3;
  m0 = (xcd * mt_per_x + (k2 >> ntl2)) * 256;
  n0 = (k2 & ((1 << ntl2) - 1)) * 128;
}

// ---------------------------------------------------------------------------
// Fused layer GEMM + minGRU gate + scan phase A (256x128 tile, 4 waves).
// Btf[2048,K]: rows [b*64,b*64+32)=Wz cols, +32=Wh cols for j-block b.
// Per wave: 64-col slice -> tn 0,1 = zpre, tn 2,3 = hpre for j = jb+tn*16+r.
// Wave covers 128 rows = 2 scan chunks of 64 (tm 0-3 / tm 4-7); composition
// order identical to the verified version -> identical cA/cB.
// ---------------------------------------------------------------------------
__global__ __launch_bounds__(256, 2)
void gemm_gate(const _Float16* __restrict__ A, const _Float16* __restrict__ Btf,
               _Float16* __restrict__ zh2,
               float* __restrict__ cA, float* __restrict__ cB,
               const float* __restrict__ bz, const float* __restrict__ bh,
               int K, int ntl2, int mt_per_x) {
  __shared__ _Float16 lds[3 * 12288];   // 72 KiB ring -> 2 blocks/CU
  const int tid  = threadIdx.x;
  const int lane = tid & 63;
  const int wave = tid >> 6;
  const int wm = wave >> 1, wn = wave & 1;
  const int quad = lane >> 4, r = lane & 15;
  int m0, n0;
  xcd_map(blockIdx.x, ntl2, mt_per_x, m0, n0);

  GemmCore128 core;
  core.init(A, Btf, lds, m0, n0, K, tid);
  fv4 acc[8][4] = {};
  core.run(acc, K);

  // C/D layout: col = lane&15, row = quad*4 + reg (m89-verified).
  const int jb   = (n0 + wn * 64) >> 1;
  const int row0 = m0 + wm * 128 + quad * 4;
  const int cb   = (m0 >> 6) + wm * 2;   // first chunk index of this wave
#pragma unroll
  for (int tn = 0; tn < 2; ++tn) {
    const int j = jb + tn * 16 + r;
    const float bzv = bz[j];
    const float bhv = bh[j];
#pragma unroll
    for (int tg = 0; tg < 2; ++tg) {     // 64-row chunk within the wave
      float qA[4], qB[4];
#pragma unroll
      for (int tq = 0; tq < 4; ++tq) {
        const int tm = tg * 4 + tq;
        float sA = 1.0f, sB = 0.0f;
#pragma unroll
        for (int r2 = 0; r2 < 4; ++r2) {
          const float zpre = acc[tm][tn][r2] + bzv;
          const float hpre = acc[tm][tn + 2][r2] + bhv;
          const float z = 1.0f / (1.0f + __expf(-zpre));
          const _Float16 a16 = (_Float16)(1.0f - z);
          const _Float16 b16 = (_Float16)(z * hpre);
          hv2 ab = {a16, b16};
          *(hv2*)(zh2 + ((size_t)(row0 + tm * 16 + r2) * 1024 + j) * 2) = ab;
          const float af = (float)a16, bf = (float)b16;
          sB = af * sB + bf;   // ordered fold, r2 ascending
          sA = sA * af;
        }
        qA[tq] = sA; qB[tq] = sB;
      }
      // inclusive scan across quads (rows 16tq+4q+r2; quad ascending)
#pragma unroll
      for (int tq = 0; tq < 4; ++tq) {
        float Av = qA[tq], Bv = qB[tq];
        float Ap = __shfl_up(Av, 16, 64);
        float Bp = __shfl_up(Bv, 16, 64);
        if (quad >= 1) { Bv = Av * Bp + Bv; Av = Ap * Av; }
        Ap = __shfl_up(Av, 32, 64);
        Bp = __shfl_up(Bv, 32, 64);
        if (quad >= 2) { Bv = Av * Bp + Bv; Av = Ap * Av; }
        qA[tq] = Av; qB[tq] = Bv;
      }
      if (quad == 3) {   // lane holds full 16-row composition per tq
        float CA = 1.0f, CB = 0.0f;
#pragma unroll
        for (int tq = 0; tq < 4; ++tq) { CB = qA[tq] * CB + qB[tq]; CA *= qA[tq]; }
        cA[(size_t)(cb + tg) * 1024 + j] = CA;
        cB[(size_t)(cb + tg) * 1024 + j] = CB;
      }
    }
  }
}

// ---------------------------------------------------------------------------
// Plain GEMM (FC head): C[M,N] fp32 = A[M,K] f16 @ Bt[N,K]^T + bias
// ---------------------------------------------------------------------------
__global__ __launch_bounds__(256, 2)
void gemm_f16_bt(const _Float16* __restrict__ A, const _Float16* __restrict__ Bt,
                 float* __restrict__ C, const float* __restrict__ bias,
                 int N, int K, int ntl2, int mt_per_x) {
  __shared__ _Float16 lds[3 * 12288];
  const int tid  = threadIdx.x;
  const int lane = tid & 63;
  const int wave = tid >> 6;
  const int wm = wave >> 1, wn = wave & 1;
  const int quad = lane >> 4, r = lane & 15;
  int m0, n0;
  xcd_map(blockIdx.x, ntl2, mt_per_x, m0, n0);

  GemmCore128 core;
  core.init(A, Bt, lds, m0, n0, K, tid);
  fv4 acc[8][4] = {};
  core.run(acc, K);

  const int col0 = n0 + wn * 64 + r;
  const int row0 = m0 + wm * 128 + quad * 4;
#pragma unroll
  for (int tn = 0; tn < 4; ++tn) {
    const int col = col0 + tn * 16;
    const float bs = bias[col];
#pragma unroll
    for (int tm = 0; tm < 8; ++tm) {
#pragma unroll
      for (int r2 = 0; r2 < 4; ++r2) {
        C[(size_t)(row0 + tm * 16 + r2) * N + col] = acc[tm][tn][r2] + bs;
      }
    }
  }
}

// ---------------------------------------------------------------------------
// elementwise fp32 -> f16
// ---------------------------------------------------------------------------
__global__ void cvt_f16(const float* __restrict__ x, _Float16* __restrict__ y) {
  size_t i = ((size_t)blockIdx.x * 256 + threadIdx.x) * 4;
  fv4 v = *(const fv4*)(x + i);
  *(hv4*)(y + i) = __builtin_convertvector(v, hv4);
}

// ---------------------------------------------------------------------------
// W[K,N] fp32 -> Wt f16; cols j = bx*32+i -> output rows bx*mult + off + i.
// ---------------------------------------------------------------------------
__global__ void transpose_cvt(const float* __restrict__ W, _Float16* __restrict__ Wt,
                              int K, int N, int mult, int off) {
  __shared__ float tile[32][33];
  const int tx = threadIdx.x, ty = threadIdx.y;
  const int n  = blockIdx.x * 32 + tx;
  const int kb = blockIdx.y * 32;
  for (int i = ty; i < 32; i += 8)
    tile[i][tx] = W[(size_t)(kb + i) * N + n];
  __syncthreads();
  const int k = kb + tx;
  for (int i = ty; i < 32; i += 8)
    Wt[(size_t)(blockIdx.x * mult + off + i) * K + k] = (_Float16)tile[tx][i];
}

// ---------------------------------------------------------------------------
// phase B: wave-parallel Hillis-Steele over the 64 chunks (lane = chunk).
// hcy[c] = h entering chunk c (exclusive scan, h0 = 0).
// ---------------------------------------------------------------------------
__global__ void scan_phaseB(const float* __restrict__ cA, const float* __restrict__ cB,
                            float* __restrict__ hcy) {
  const int gtid = blockIdx.x * 256 + threadIdx.x;  // 2048 waves * 64
  const int lane = gtid & 63;
  const int wid  = gtid >> 6;
  const int h  = (wid & 255) * 4;
  const int bb = wid >> 8;
  const size_t o = (size_t)(bb * 64 + lane) * 1024 + h;
  fv4 Aa = *(const fv4*)(cA + o);
  fv4 Bv = *(const fv4*)(cB + o);
#pragma unroll
  for (int d = 1; d < 64; d <<= 1) {
    fv4 Ap, Bp;
#pragma unroll
    for (int k = 0; k < 4; ++k) {
      Ap[k] = __shfl_up(Aa[k], d, 64);
      Bp[k] = __shfl_up(Bv[k], d, 64);
    }
    if (lane >= d) {
      Bv = Aa * Bp + Bv;
      Aa = Ap * Aa;
    }
  }
  fv4 hc;
#pragma unroll
  for (int k = 0; k < 4; ++k) hc[k] = __shfl_up(Bv[k], 1, 64);
  if (lane == 0) { hc.x = 0.f; hc.y = 0.f; hc.z = 0.f; hc.w = 0.f; }
  *(fv4*)(hcy + o) = hc;
}

// phase C: replay chunk with correct carry, emit h (f16, [M,1024])
__global__ void scan_phaseC(const _Float16* __restrict__ zh2,
                            const float* __restrict__ hcy,
                            _Float16* __restrict__ hout) {
  const int idx = blockIdx.x * 256 + threadIdx.x;
  const int h  = (idx & 255) * 4;
  const int c  = (idx >> 8) & 63;
  const int bb = idx >> 14;
  const size_t base = ((size_t)(bb * 4096 + c * 64) * 1024 + h) * 2;
  const size_t ob   = (size_t)(bb * 4096 + c * 64) * 1024 + h;
  const size_t o    = (size_t)(bb * 64 + c) * 1024 + h;
  fv4 hc = *(const fv4*)(hcy + o);
#pragma unroll 4
  for (int t = 0; t < 64; ++t) {
    hv8 v = *(const hv8*)(zh2 + base + (size_t)t * 2048);
    fv4 av = __builtin_convertvector(__builtin_shufflevector(v, v, 0, 2, 4, 6), fv4);
    fv4 bv = __builtin_convertvector(__builtin_shufflevector(v, v, 1, 3, 5, 7), fv4);
    hc = av * hc + bv;
    *(hv4*)(hout + ob + (size_t)t * 1024) = __builtin_convertvector(hc, hv4);
  }
}

// ---------------------------------------------------------------------------
extern "C" void kernel_launch(void* const* d_in, const int* in_sizes, int n_in,
                              void* d_out, int out_size, void* d_ws, size_t ws_size,
                              hipStream_t stream) {
  const float* x   = (const float*)d_in[0];
  const float* Wz0 = (const float*)d_in[1];
  const float* bz0 = (const float*)d_in[2];
  const float* Wh0 = (const float*)d_in[3];
  const float* bh0 = (const float*)d_in[4];
  const float* Wz1 = (const float*)d_in[5];
  const float* bz1 = (const float*)d_in[6];
  const float* Wh1 = (const float*)d_in[7];
  const float* bh1 = (const float*)d_in[8];
  const float* Wfc = (const float*)d_in[9];
  const float* bfc = (const float*)d_in[10];

  const int Mrows = 32768;  // B*T
  const int H = 1024, Din = 512, Dout = 512;

  // workspace layout (~205 MiB)
  char* w = (char*)d_ws;
  _Float16* zh2   = (_Float16*)w; w += (size_t)Mrows * 2 * H * 2;   // 128 MiB
  _Float16* hx    = (_Float16*)w; w += (size_t)Mrows * H * 2;       //  64 MiB
  _Float16* Wzh0t = (_Float16*)w; w += (size_t)2 * H * Din * 2;
  _Float16* Wzh1t = (_Float16*)w; w += (size_t)2 * H * H * 2;
  _Float16* Wft   = (_Float16*)w; w += (size_t)Dout * H * 2;
  float*    cA    = (float*)w;    w += (size_t)8 * 64 * H * 4;
  float*    cB    = (float*)w;    w += (size_t)8 * 64 * H * 4;
  float*    hcy   = (float*)w;    w += (size_t)8 * 64 * H * 4;
  _Float16* Xb    = hx;  // aliased: x(f16) dead before h0 is written

  // --- input conversions (fused z|h row mapping for layer weights) ---
  cvt_f16<<<Mrows * Din / 1024, 256, 0, stream>>>(x, Xb);
  transpose_cvt<<<dim3(H / 32, Din / 32), dim3(32, 8), 0, stream>>>(Wz0, Wzh0t, Din, H, 64, 0);
  transpose_cvt<<<dim3(H / 32, Din / 32), dim3(32, 8), 0, stream>>>(Wh0, Wzh0t, Din, H, 64, 32);
  transpose_cvt<<<dim3(H / 32, H / 32),   dim3(32, 8), 0, stream>>>(Wz1, Wzh1t, H, H, 64, 0);
  transpose_cvt<<<dim3(H / 32, H / 32),   dim3(32, 8), 0, stream>>>(Wh1, Wzh1t, H, H, 64, 32);
  transpose_cvt<<<dim3(Dout / 32, H / 32), dim3(32, 8), 0, stream>>>(Wfc, Wft, H, Dout, 32, 0);

  // layer GEMM: 256x128 tiles -> 128 mtiles x 16 ntiles = 2048 blocks,
  // ntl2=4, 16 mtiles per XCD; 2 blocks co-resident per CU.
  // --- layer 0 ---
  gemm_gate<<<2048, 256, 0, stream>>>(Xb, Wzh0t, zh2, cA, cB, bz0, bh0, Din, 4, 16);
  scan_phaseB<<<512, 256, 0, stream>>>(cA, cB, hcy);
  scan_phaseC<<<512, 256, 0, stream>>>(zh2, hcy, hx);

  // --- layer 1 ---
  gemm_gate<<<2048, 256, 0, stream>>>(hx, Wzh1t, zh2, cA, cB, bz1, bh1, H, 4, 16);
  scan_phaseB<<<512, 256, 0, stream>>>(cA, cB, hcy);
  scan_phaseC<<<512, 256, 0, stream>>>(zh2, hcy, hx);

  // --- FC head: 128 mtiles x 4 ntiles = 512 blocks, ntl2=2 ---
  gemm_f16_bt<<<512, 256, 0, stream>>>(hx, Wft, (float*)d_out, bfc, Dout, H, 2, 16);
}

// Round 6
// 491.573 us; speedup vs baseline: 1.0626x; 1.0626x over previous
//
#include <hip/hip_runtime.h>

typedef __attribute__((ext_vector_type(4))) float fv4;
typedef __attribute__((ext_vector_type(8))) _Float16 hv8;
typedef __attribute__((ext_vector_type(4))) _Float16 hv4;
typedef __attribute__((ext_vector_type(2))) _Float16 hv2;

// ---------------------------------------------------------------------------
// async global->LDS 16B copy (wave-uniform LDS base + lane*16 semantics)
// ---------------------------------------------------------------------------
__device__ __forceinline__ void gload16(const void* g, void* l) {
  __builtin_amdgcn_global_load_lds(
      (const __attribute__((address_space(1))) unsigned int*)g,
      (__attribute__((address_space(3))) unsigned int*)l, 16, 0, 0);
}

// ---------------------------------------------------------------------------
// 256x256 tile GEMM core, 8 waves (2M x 4N), per-wave 128x64 output.
// K in BK=32 steps through a 4-deep LDS ring (4 x 32 KiB = 128 KiB).
// FULL LDS->REG SOFTWARE PIPELINE (completes R4's partial prefetch):
//   per step s: vmcnt(4) [slot s+1 landed] -> barrier [collective; also
//   certifies all waves' slot s-1 reads done] -> stage(s+3) [overwrites
//   slot s-1, safe] -> read a47(slot s) [drains under cluster 1] ->
//   16 MFMA cluster1 (a03_cur x b_cur; lgkmcnt(4) allows a47 in flight) ->
//   read b_nxt + a03_nxt (slot s+1) [drains under cluster 2] ->
//   16 MFMA cluster2 (a47 x b_cur; lgkmcnt(8) allows nxt in flight).
// Steady state: ZERO exposed LDS-read cycles -- the 8-wave read convoy
// (~1150 cyc/CU/step) fully overlaps the MFMA clusters (~1242 cyc/SIMD).
// vmcnt never drains to 0 in the main loop (tail 4 -> 4 -> 0).
// Frag banks (b0/a03 <-> b1/a13) swap with STATIC names (rule #20);
// (ns-4) is even for K=512/1024 so tail parities are compile-time-fixed.
// Swizzle (measured 0 conflicts): staged-side cg=(tid&3)^((tid>>3)&3) on the
// global source, fragment-side sq=quad^((r>>1)&3) on the ds_read.
// ---------------------------------------------------------------------------
struct GemmCore256 {
  const _Float16 *ap, *bp;   // per-thread pre-swizzled global sources
  size_t rstep;              // +128 rows in elements
  _Float16* ls;
  const _Float16 *fa, *fb;   // fragment read bases (ring slot 0)
  int wv;

  __device__ __forceinline__ void init(const _Float16* A, const _Float16* Bt,
                                       _Float16* lds, int m0, int n0, int K,
                                       int tid) {
    ls = lds;
    wv = tid >> 6;
    const int lane = tid & 63;
    const int wm = wv >> 2, wn = wv & 3;
    const int quad = lane >> 4, r = lane & 15;
    const int cg = (tid & 3) ^ ((tid >> 3) & 3);   // staged-side XOR swizzle
    ap = A  + (size_t)(m0 + (tid >> 2)) * K + cg * 8;
    bp = Bt + (size_t)(n0 + (tid >> 2)) * K + cg * 8;
    rstep = (size_t)128 * K;
    const int sq = quad ^ ((r >> 1) & 3);          // fragment-side swizzle
    fa = ls + (wm * 128 + r) * 32 + sq * 8;
    fb = ls + 8192 + (wn * 64 + r) * 32 + sq * 8;
  }

  __device__ __forceinline__ void stage4(int s) {   // full ring slot s&3
    _Float16* d = ls + (s & 3) * 16384 + wv * 512;
    const _Float16* a = ap + (size_t)s * 32;
    const _Float16* b = bp + (size_t)s * 32;
    gload16(a,         d);
    gload16(a + rstep, d + 4096);
    gload16(b,         d + 8192);
    gload16(b + rstep, d + 12288);
  }

  __device__ __forceinline__ void readBA(hv8 (&b)[4], hv8 (&a)[4], int s) {
    const _Float16* fA = fa + (s & 3) * 16384;
    const _Float16* fB = fb + (s & 3) * 16384;
#pragma unroll
    for (int t = 0; t < 4; ++t) b[t] = *(const hv8*)(fB + t * 512);
#pragma unroll
    for (int t = 0; t < 4; ++t) a[t] = *(const hv8*)(fA + t * 512);
  }

  // one K-step; cur_* prefetched for slot s; nxt_* filled for slot s+1
  template <int VM, bool STAGE>
  __device__ __forceinline__ void body(fv4 acc[8][4],
                                       hv8 (&cb)[4], hv8 (&ca)[4],
                                       hv8 (&nb)[4], hv8 (&na)[4], int s) {
    if constexpr (VM >= 0)
      asm volatile("s_waitcnt vmcnt(%0)" :: "n"(VM) : "memory");
    __builtin_amdgcn_s_barrier();
    asm volatile("" ::: "memory");   // pin stage/reads below the barrier
    if (STAGE) stage4(s + 3);
    const _Float16* fA = fa + (s & 3) * 16384;
    hv8 a47[4];
#pragma unroll
    for (int t = 0; t < 4; ++t) a47[t] = *(const hv8*)(fA + (t + 4) * 512);
    __builtin_amdgcn_s_setprio(1);
#pragma unroll
    for (int tm = 0; tm < 4; ++tm)       // cluster 1: lgkmcnt(4) (a47 fly)
#pragma unroll
      for (int tn = 0; tn < 4; ++tn)
        acc[tm][tn] = __builtin_amdgcn_mfma_f32_16x16x32_f16(ca[tm], cb[tn],
                                                             acc[tm][tn], 0, 0, 0);
    __builtin_amdgcn_s_setprio(0);
    readBA(nb, na, s + 1);               // drains under cluster 2
    __builtin_amdgcn_s_setprio(1);
#pragma unroll
    for (int tm = 0; tm < 4; ++tm)       // cluster 2: lgkmcnt(8) (nxt fly)
#pragma unroll
      for (int tn = 0; tn < 4; ++tn)
        acc[tm + 4][tn] = __builtin_amdgcn_mfma_f32_16x16x32_f16(a47[tm], cb[tn],
                                                                 acc[tm + 4][tn], 0, 0, 0);
    __builtin_amdgcn_s_setprio(0);
  }

  __device__ __forceinline__ void bodyLast(fv4 acc[8][4],
                                           hv8 (&cb)[4], hv8 (&ca)[4], int s) {
    __builtin_amdgcn_s_barrier();
    asm volatile("" ::: "memory");
    const _Float16* fA = fa + (s & 3) * 16384;
    hv8 a47[4];
#pragma unroll
    for (int t = 0; t < 4; ++t) a47[t] = *(const hv8*)(fA + (t + 4) * 512);
    __builtin_amdgcn_s_setprio(1);
#pragma unroll
    for (int tm = 0; tm < 4; ++tm)
#pragma unroll
      for (int tn = 0; tn < 4; ++tn)
        acc[tm][tn] = __builtin_amdgcn_mfma_f32_16x16x32_f16(ca[tm], cb[tn],
                                                             acc[tm][tn], 0, 0, 0);
#pragma unroll
    for (int tm = 0; tm < 4; ++tm)
#pragma unroll
      for (int tn = 0; tn < 4; ++tn)
        acc[tm + 4][tn] = __builtin_amdgcn_mfma_f32_16x16x32_f16(a47[tm], cb[tn],
                                                                 acc[tm + 4][tn], 0, 0, 0);
    __builtin_amdgcn_s_setprio(0);
  }

  __device__ __forceinline__ void run(fv4 acc[8][4], int K) {
    const int ns = K >> 5;               // BK=32 steps: 16 or 32 (ns-4 even)
    stage4(0); stage4(1); stage4(2);     // prime ring 3 deep (12 outstanding)
    asm volatile("s_waitcnt vmcnt(8)" ::: "memory");   // slot 0 landed (mine)
    __builtin_amdgcn_s_barrier();                      // collective
    asm volatile("" ::: "memory");
    hv8 b0[4], a03[4], b1[4], a13[4];    // static frag banks (rule #20)
    readBA(b0, a03, 0);
    int s = 0;
    for (; s < ns - 4; s += 2) {         // (ns-4)/2 pairs, ends at s = ns-4
      body<4, true>(acc, b0, a03, b1, a13, s);
      body<4, true>(acc, b1, a13, b0, a03, s + 1);
    }
    body<4, true >(acc, b0, a03, b1, a13, ns - 4);  // stages slot ns-1 (last)
    body<4, false>(acc, b1, a13, b0, a03, ns - 3);  // guard: slot ns-2 landed
    body<0, false>(acc, b0, a03, b1, a13, ns - 2);  // guard: slot ns-1 landed
    bodyLast(acc, b1, a13, ns - 1);
  }
};

// XCD-colocation block swizzle (tile = 256): blocks sharing one A-strip get
// linear ids congruent mod 8 -> same XCD -> A-strip hits in its L2.
__device__ __forceinline__ void xcd_map(int bid, int ntl2, int mt_per_x,
                                        int& m0, int& n0) {
  const int xcd = bid & 7;
  const int k2  = bid >> 3;
  m0 = (xcd * mt_per_x + (k2 >> ntl2)) * 256;
  n0 = (k2 & ((1 << ntl2) - 1)) * 256;
}

// ---------------------------------------------------------------------------
// Fused layer GEMM + minGRU gate + scan phase A (256-tile, 8 waves).
// Btf[2048,K]: rows [b*64,b*64+32)=Wz cols, +32=Wh cols for j-block b.
// Per wave: 64-col slice -> tn 0,1 = zpre, tn 2,3 = hpre for j = jb+tn*16+r.
// Wave covers 128 rows = 2 scan chunks of 64 (tm 0-3 / tm 4-7); composition
// order identical to the verified version -> bit-identical cA/cB.
// ---------------------------------------------------------------------------
__global__ __launch_bounds__(512, 2)
void gemm_gate(const _Float16* __restrict__ A, const _Float16* __restrict__ Btf,
               _Float16* __restrict__ zh2,
               float* __restrict__ cA, float* __restrict__ cB,
               const float* __restrict__ bz, const float* __restrict__ bh,
               int K, int ntl2, int mt_per_x) {
  __shared__ _Float16 lds[4 * 16384];   // 128 KiB ring
  const int tid  = threadIdx.x;
  const int lane = tid & 63;
  const int wave = tid >> 6;
  const int wm = wave >> 2, wn = wave & 3;
  const int quad = lane >> 4, r = lane & 15;
  int m0, n0;
  xcd_map(blockIdx.x, ntl2, mt_per_x, m0, n0);

  GemmCore256 core;
  core.init(A, Btf, lds, m0, n0, K, tid);
  fv4 acc[8][4] = {};
  core.run(acc, K);

  // C/D layout: col = lane&15, row = quad*4 + reg (m89-verified).
  const int jb   = (n0 + wn * 64) >> 1;
  const int row0 = m0 + wm * 128 + quad * 4;
  const int cb   = (m0 >> 6) + wm * 2;   // first chunk index of this wave
#pragma unroll
  for (int tn = 0; tn < 2; ++tn) {
    const int j = jb + tn * 16 + r;
    const float bzv = bz[j];
    const float bhv = bh[j];
#pragma unroll
    for (int tg = 0; tg < 2; ++tg) {     // 64-row chunk within the wave
      float qA[4], qB[4];
#pragma unroll
      for (int tq = 0; tq < 4; ++tq) {
        const int tm = tg * 4 + tq;
        float sA = 1.0f, sB = 0.0f;
#pragma unroll
        for (int r2 = 0; r2 < 4; ++r2) {
          const float zpre = acc[tm][tn][r2] + bzv;
          const float hpre = acc[tm][tn + 2][r2] + bhv;
          const float z = 1.0f / (1.0f + __expf(-zpre));
          const _Float16 a16 = (_Float16)(1.0f - z);
          const _Float16 b16 = (_Float16)(z * hpre);
          hv2 ab = {a16, b16};
          *(hv2*)(zh2 + ((size_t)(row0 + tm * 16 + r2) * 1024 + j) * 2) = ab;
          const float af = (float)a16, bf = (float)b16;
          sB = af * sB + bf;   // ordered fold, r2 ascending
          sA = sA * af;
        }
        qA[tq] = sA; qB[tq] = sB;
      }
      // inclusive scan across quads (rows 16tq+4q+r2; quad ascending)
#pragma unroll
      for (int tq = 0; tq < 4; ++tq) {
        float Av = qA[tq], Bv = qB[tq];
        float Ap = __shfl_up(Av, 16, 64);
        float Bp = __shfl_up(Bv, 16, 64);
        if (quad >= 1) { Bv = Av * Bp + Bv; Av = Ap * Av; }
        Ap = __shfl_up(Av, 32, 64);
        Bp = __shfl_up(Bv, 32, 64);
        if (quad >= 2) { Bv = Av * Bp + Bv; Av = Ap * Av; }
        qA[tq] = Av; qB[tq] = Bv;
      }
      if (quad == 3) {   // lane holds full 16-row composition per tq
        float CA = 1.0f, CB = 0.0f;
#pragma unroll
        for (int tq = 0; tq < 4; ++tq) { CB = qA[tq] * CB + qB[tq]; CA *= qA[tq]; }
        cA[(size_t)(cb + tg) * 1024 + j] = CA;
        cB[(size_t)(cb + tg) * 1024 + j] = CB;
      }
    }
  }
}

// ---------------------------------------------------------------------------
// Plain GEMM (FC head): C[M,N] fp32 = A[M,K] f16 @ Bt[N,K]^T + bias
// ---------------------------------------------------------------------------
__global__ __launch_bounds__(512, 2)
void gemm_f16_bt(const _Float16* __restrict__ A, const _Float16* __restrict__ Bt,
                 float* __restrict__ C, const float* __restrict__ bias,
                 int N, int K, int ntl2, int mt_per_x) {
  __shared__ _Float16 lds[4 * 16384];
  const int tid  = threadIdx.x;
  const int lane = tid & 63;
  const int wave = tid >> 6;
  const int wm = wave >> 2, wn = wave & 3;
  const int quad = lane >> 4, r = lane & 15;
  int m0, n0;
  xcd_map(blockIdx.x, ntl2, mt_per_x, m0, n0);

  GemmCore256 core;
  core.init(A, Bt, lds, m0, n0, K, tid);
  fv4 acc[8][4] = {};
  core.run(acc, K);

  const int col0 = n0 + wn * 64 + r;
  const int row0 = m0 + wm * 128 + quad * 4;
#pragma unroll
  for (int tn = 0; tn < 4; ++tn) {
    const int col = col0 + tn * 16;
    const float bs = bias[col];
#pragma unroll
    for (int tm = 0; tm < 8; ++tm) {
#pragma unroll
      for (int r2 = 0; r2 < 4; ++r2) {
        C[(size_t)(row0 + tm * 16 + r2) * N + col] = acc[tm][tn][r2] + bs;
      }
    }
  }
}

// ---------------------------------------------------------------------------
// elementwise fp32 -> f16
// ---------------------------------------------------------------------------
__global__ void cvt_f16(const float* __restrict__ x, _Float16* __restrict__ y) {
  size_t i = ((size_t)blockIdx.x * 256 + threadIdx.x) * 4;
  fv4 v = *(const fv4*)(x + i);
  *(hv4*)(y + i) = __builtin_convertvector(v, hv4);
}

// ---------------------------------------------------------------------------
// W[K,N] fp32 -> Wt f16; cols j = bx*32+i -> output rows bx*mult + off + i.
// ---------------------------------------------------------------------------
__global__ void transpose_cvt(const float* __restrict__ W, _Float16* __restrict__ Wt,
                              int K, int N, int mult, int off) {
  __shared__ float tile[32][33];
  const int tx = threadIdx.x, ty = threadIdx.y;
  const int n  = blockIdx.x * 32 + tx;
  const int kb = blockIdx.y * 32;
  for (int i = ty; i < 32; i += 8)
    tile[i][tx] = W[(size_t)(kb + i) * N + n];
  __syncthreads();
  const int k = kb + tx;
  for (int i = ty; i < 32; i += 8)
    Wt[(size_t)(blockIdx.x * mult + off + i) * K + k] = (_Float16)tile[tx][i];
}

// ---------------------------------------------------------------------------
// phase B: wave-parallel Hillis-Steele over the 64 chunks (lane = chunk).
// hcy[c] = h entering chunk c (exclusive scan, h0 = 0).
// ---------------------------------------------------------------------------
__global__ void scan_phaseB(const float* __restrict__ cA, const float* __restrict__ cB,
                            float* __restrict__ hcy) {
  const int gtid = blockIdx.x * 256 + threadIdx.x;  // 2048 waves * 64
  const int lane = gtid & 63;
  const int wid  = gtid >> 6;
  const int h  = (wid & 255) * 4;
  const int bb = wid >> 8;
  const size_t o = (size_t)(bb * 64 + lane) * 1024 + h;
  fv4 Aa = *(const fv4*)(cA + o);
  fv4 Bv = *(const fv4*)(cB + o);
#pragma unroll
  for (int d = 1; d < 64; d <<= 1) {
    fv4 Ap, Bp;
#pragma unroll
    for (int k = 0; k < 4; ++k) {
      Ap[k] = __shfl_up(Aa[k], d, 64);
      Bp[k] = __shfl_up(Bv[k], d, 64);
    }
    if (lane >= d) {
      Bv = Aa * Bp + Bv;
      Aa = Ap * Aa;
    }
  }
  fv4 hc;
#pragma unroll
  for (int k = 0; k < 4; ++k) hc[k] = __shfl_up(Bv[k], 1, 64);
  if (lane == 0) { hc.x = 0.f; hc.y = 0.f; hc.z = 0.f; hc.w = 0.f; }
  *(fv4*)(hcy + o) = hc;
}

// phase C: replay chunk with correct carry, emit h (f16, [M,1024])
__global__ void scan_phaseC(const _Float16* __restrict__ zh2,
                            const float* __restrict__ hcy,
                            _Float16* __restrict__ hout) {
  const int idx = blockIdx.x * 256 + threadIdx.x;
  const int h  = (idx & 255) * 4;
  const int c  = (idx >> 8) & 63;
  const int bb = idx >> 14;
  const size_t base = ((size_t)(bb * 4096 + c * 64) * 1024 + h) * 2;
  const size_t ob   = (size_t)(bb * 4096 + c * 64) * 1024 + h;
  const size_t o    = (size_t)(bb * 64 + c) * 1024 + h;
  fv4 hc = *(const fv4*)(hcy + o);
#pragma unroll 4
  for (int t = 0; t < 64; ++t) {
    hv8 v = *(const hv8*)(zh2 + base + (size_t)t * 2048);
    fv4 av = __builtin_convertvector(__builtin_shufflevector(v, v, 0, 2, 4, 6), fv4);
    fv4 bv = __builtin_convertvector(__builtin_shufflevector(v, v, 1, 3, 5, 7), fv4);
    hc = av * hc + bv;
    *(hv4*)(hout + ob + (size_t)t * 1024) = __builtin_convertvector(hc, hv4);
  }
}

// ---------------------------------------------------------------------------
extern "C" void kernel_launch(void* const* d_in, const int* in_sizes, int n_in,
                              void* d_out, int out_size, void* d_ws, size_t ws_size,
                              hipStream_t stream) {
  const float* x   = (const float*)d_in[0];
  const float* Wz0 = (const float*)d_in[1];
  const float* bz0 = (const float*)d_in[2];
  const float* Wh0 = (const float*)d_in[3];
  const float* bh0 = (const float*)d_in[4];
  const float* Wz1 = (const float*)d_in[5];
  const float* bz1 = (const float*)d_in[6];
  const float* Wh1 = (const float*)d_in[7];
  const float* bh1 = (const float*)d_in[8];
  const float* Wfc = (const float*)d_in[9];
  const float* bfc = (const float*)d_in[10];

  const int Mrows = 32768;  // B*T
  const int H = 1024, Din = 512, Dout = 512;

  // workspace layout (~205 MiB)
  char* w = (char*)d_ws;
  _Float16* zh2   = (_Float16*)w; w += (size_t)Mrows * 2 * H * 2;   // 128 MiB
  _Float16* hx    = (_Float16*)w; w += (size_t)Mrows * H * 2;       //  64 MiB
  _Float16* Wzh0t = (_Float16*)w; w += (size_t)2 * H * Din * 2;
  _Float16* Wzh1t = (_Float16*)w; w += (size_t)2 * H * H * 2;
  _Float16* Wft   = (_Float16*)w; w += (size_t)Dout * H * 2;
  float*    cA    = (float*)w;    w += (size_t)8 * 64 * H * 4;
  float*    cB    = (float*)w;    w += (size_t)8 * 64 * H * 4;
  float*    hcy   = (float*)w;    w += (size_t)8 * 64 * H * 4;
  _Float16* Xb    = hx;  // aliased: x(f16) dead before h0 is written

  // --- input conversions (fused z|h row mapping for layer weights) ---
  cvt_f16<<<Mrows * Din / 1024, 256, 0, stream>>>(x, Xb);
  transpose_cvt<<<dim3(H / 32, Din / 32), dim3(32, 8), 0, stream>>>(Wz0, Wzh0t, Din, H, 64, 0);
  transpose_cvt<<<dim3(H / 32, Din / 32), dim3(32, 8), 0, stream>>>(Wh0, Wzh0t, Din, H, 64, 32);
  transpose_cvt<<<dim3(H / 32, H / 32),   dim3(32, 8), 0, stream>>>(Wz1, Wzh1t, H, H, 64, 0);
  transpose_cvt<<<dim3(H / 32, H / 32),   dim3(32, 8), 0, stream>>>(Wh1, Wzh1t, H, H, 64, 32);
  transpose_cvt<<<dim3(Dout / 32, H / 32), dim3(32, 8), 0, stream>>>(Wfc, Wft, H, Dout, 32, 0);

  // layer GEMM: 256x256 tiles -> 128 mtiles x 8 ntiles = 1024 blocks,
  // ntl2=3, 16 mtiles per XCD.
  // --- layer 0 ---
  gemm_gate<<<1024, 512, 0, stream>>>(Xb, Wzh0t, zh2, cA, cB, bz0, bh0, Din, 3, 16);
  scan_phaseB<<<512, 256, 0, stream>>>(cA, cB, hcy);
  scan_phaseC<<<512, 256, 0, stream>>>(zh2, hcy, hx);

  // --- layer 1 ---
  gemm_gate<<<1024, 512, 0, stream>>>(hx, Wzh1t, zh2, cA, cB, bz1, bh1, H, 3, 16);
  scan_phaseB<<<512, 256, 0, stream>>>(cA, cB, hcy);
  scan_phaseC<<<512, 256, 0, stream>>>(zh2, hcy, hx);

  // --- FC head: 128 mtiles x 2 ntiles = 256 blocks, ntl2=1 ---
  gemm_f16_bt<<<256, 512, 0, stream>>>(hx, Wft, (float*)d_out, bfc, Dout, H, 1, 16);
}